// Round 2
// baseline (3301.541 us; speedup 1.0000x reference)
//
#include <hip/hip_runtime.h>
#include <math.h>

// ---------------------------------------------------------------------------
// SambaBlock. Round 1: shrink workspace 504 MB -> 243 MB (round-0 crash
// diagnosed as d_ws overrun). All scratch bf16; heavy region reuse:
//   R0 region: xr -> dt -> z -> (part of f1)
//   Y region:  y -> yg (in-place gate)
//   f2 produced in two 768-channel halves + split-K final GEMM.
// ---------------------------------------------------------------------------

using u16 = unsigned short;
typedef __bf16 bf8_t __attribute__((ext_vector_type(8)));
typedef float f32x4 __attribute__((ext_vector_type(4)));

#define NT    32768   // B * L
#define LSEQ  4096
#define DIMC  384
#define DIN   768
#define HIDC  1536

__device__ __forceinline__ float bf2f(u16 u) {
  return __uint_as_float(((unsigned int)u) << 16);
}
__device__ __forceinline__ u16 f2b(float f) {
  unsigned int x = __float_as_uint(f);
  return (u16)((x + 0x7FFFu + ((x >> 16) & 1u)) >> 16);  // RNE
}

// ---------------------------------------------------------------------------
// Workspace layout (bytes). TOTAL = 242,962,432 (~231.7 MiB).
//   R0  [0,          50331648): bf16 NT*768  xr / dt / z ; f1 part 1
//   XC  [50331648,  100663296): bf16 NT*768  xc          ; f1 part 2
//   XDB [100663296, 110624768): bf16 NT*152  xdb         ; f2-half (50331648,
//   DTA [110624768, 112721920): bf16 NT*32     spans XDB..part of Y, all dead)
//   XN  [112721920, 137887744): bf16 NT*384  xn1/xn2
//   Y   [137887744, 188219392): bf16 NT*768  y -> yg (in place)
//   X2  [188219392, 238551040): f32  NT*384  residual stream
//   WB  [238551040, 242962432): bf16 weights (2205696 elems)
// ---------------------------------------------------------------------------
#define OFF_R0   0ull
#define OFF_XC   50331648ull
#define OFF_XDB  100663296ull
#define OFF_DTA  110624768ull
#define OFF_XN   112721920ull
#define OFF_Y    137887744ull
#define OFF_X2   188219392ull
#define OFF_WB   238551040ull
// weight sub-offsets (u16 elements)
#define WOF_WIN  0
#define WOF_WXP  589824
#define WOF_WOUT 706560
#define WOF_W1   1001472
#define WOF_W2   1591296        // stored as [2][384][768] half-split
#define WOF_WDT  2181120        // padded (768,32), cols 24..31 zero
#define W_TOTAL  2205696

// ---------------------------------------------------------------------------
// fp32 -> bf16 weight conversion. W2 is permuted to half-split layout:
// W2h[h][n][k] = W2[n][h*768+k]. W_dt zero-padded to K=32.
// ---------------------------------------------------------------------------
__global__ __launch_bounds__(256)
void convert_w_k(const float* __restrict__ Win, const float* __restrict__ Wxp,
                 const float* __restrict__ Wout, const float* __restrict__ W1,
                 const float* __restrict__ W2, const float* __restrict__ Wdt,
                 u16* __restrict__ dst) {
  int i = blockIdx.x * 256 + threadIdx.x;
  float v;
  if (i < WOF_WXP)       v = Win[i];
  else if (i < WOF_WOUT) v = Wxp[i - WOF_WXP];
  else if (i < WOF_W1)   v = Wout[i - WOF_WOUT];
  else if (i < WOF_W2)   v = W1[i - WOF_W1];
  else if (i < WOF_WDT) {
    int j = i - WOF_W2;
    int h = j / 294912; int rem = j - h * 294912;
    int r = rem / 768;  int k = rem - r * 768;
    v = W2[r * 1536 + h * 768 + k];
  } else {
    int j = i - WOF_WDT; int c = j & 31; int r = j >> 5;
    v = (c < 24) ? Wdt[r * 24 + c] : 0.f;
  }
  dst[i] = f2b(v);
}

// ---------------------------------------------------------------------------
// LayerNorm over rows of 384, one wave per row, bf16 output.
// ---------------------------------------------------------------------------
__global__ __launch_bounds__(256)
void ln_k(const float* __restrict__ x, const float* __restrict__ g,
          const float* __restrict__ b, u16* __restrict__ out) {
  const int row  = (blockIdx.x << 2) + (threadIdx.x >> 6);
  const int lane = threadIdx.x & 63;
  const float* xr = x + (size_t)row * DIMC;
  float v[6]; float s = 0.f;
#pragma unroll
  for (int j = 0; j < 6; ++j) { v[j] = xr[lane + (j << 6)]; s += v[j]; }
#pragma unroll
  for (int m = 1; m < 64; m <<= 1) s += __shfl_xor(s, m);
  const float mu = s * (1.f / DIMC);
  float q = 0.f;
#pragma unroll
  for (int j = 0; j < 6; ++j) { float dv = v[j] - mu; q += dv * dv; }
#pragma unroll
  for (int m = 1; m < 64; m <<= 1) q += __shfl_xor(q, m);
  const float rs = rsqrtf(q * (1.f / DIMC) + 1e-5f);
  u16* orow = out + (size_t)row * DIMC;
#pragma unroll
  for (int j = 0; j < 6; ++j) {
    int c = lane + (j << 6);
    orow[c] = f2b((v[j] - mu) * rs * g[c] + b[c]);
  }
}

// ---------------------------------------------------------------------------
// bf16 MFMA GEMM: C[M,N] = A[M,K] @ W[N,K]^T (+bias +resid, opt softplus).
// Block 256 = 4 waves, tile 64x64, BK=32. M assumed multiple of 64 (=32768);
// N guarded. Verified gfx950 16x16x32 layouts (m89/m91):
//   frag[j] = Mat[lane&15][(lane>>4)*8+j];  D: m=(lane>>4)*4+r, n=lane&15.
// ---------------------------------------------------------------------------
template<int OUT_BF16, int ACT>
__global__ __launch_bounds__(256)
void gemm_k(const u16* __restrict__ A, const u16* __restrict__ Bw,
            void* __restrict__ Cout, const float* __restrict__ bias,
            const float* __restrict__ resid, int N, int K) {
  __shared__ __align__(16) u16 As[64][40];
  __shared__ __align__(16) u16 Bs[64][40];
  const int tid  = threadIdx.x;
  const int lane = tid & 63;
  const int wave = tid >> 6;
  const int bn = blockIdx.x << 6;
  const int bm = blockIdx.y << 6;
  const int srow = tid >> 2;
  const int scol = (tid & 3) << 3;
  const int wm = (wave >> 1) << 5;
  const int wn = (wave & 1) << 5;
  const int fr = lane & 15;
  const int fq = lane >> 4;
  f32x4 acc[2][2] = {};
  for (int k0 = 0; k0 < K; k0 += 32) {
    uint4 av = *(const uint4*)(A + (size_t)(bm + srow) * K + k0 + scol);
    uint4 bv = make_uint4(0u, 0u, 0u, 0u);
    if (bn + srow < N)
      bv = *(const uint4*)(Bw + (size_t)(bn + srow) * K + k0 + scol);
    *(uint4*)&As[srow][scol] = av;
    *(uint4*)&Bs[srow][scol] = bv;
    __syncthreads();
    bf8_t a0 = *(const bf8_t*)&As[wm + fr][fq << 3];
    bf8_t a1 = *(const bf8_t*)&As[wm + 16 + fr][fq << 3];
    bf8_t b0 = *(const bf8_t*)&Bs[wn + fr][fq << 3];
    bf8_t b1 = *(const bf8_t*)&Bs[wn + 16 + fr][fq << 3];
    acc[0][0] = __builtin_amdgcn_mfma_f32_16x16x32_bf16(a0, b0, acc[0][0], 0, 0, 0);
    acc[0][1] = __builtin_amdgcn_mfma_f32_16x16x32_bf16(a0, b1, acc[0][1], 0, 0, 0);
    acc[1][0] = __builtin_amdgcn_mfma_f32_16x16x32_bf16(a1, b0, acc[1][0], 0, 0, 0);
    acc[1][1] = __builtin_amdgcn_mfma_f32_16x16x32_bf16(a1, b1, acc[1][1], 0, 0, 0);
    __syncthreads();
  }
#pragma unroll
  for (int i = 0; i < 2; ++i) {
#pragma unroll
    for (int j = 0; j < 2; ++j) {
      const int col = bn + wn + (j << 4) + fr;
      if (col >= N) continue;
      const float bv = bias ? bias[col] : 0.f;
#pragma unroll
      for (int r = 0; r < 4; ++r) {
        const int row = bm + wm + (i << 4) + (fq << 2) + r;
        float v = acc[i][j][r] + bv;
        if (resid) v += resid[(size_t)row * N + col];
        if (ACT == 1) v = (v > 20.f) ? v : log1pf(__expf(v));  // softplus
        if (OUT_BF16) ((u16*)Cout)[(size_t)row * N + col] = f2b(v);
        else          ((float*)Cout)[(size_t)row * N + col] = v;
      }
    }
  }
}

// ---------------------------------------------------------------------------
// Causal depthwise conv1d (k=4, left pad 3) + SiLU. xr stride = 768 now.
// ---------------------------------------------------------------------------
__global__ __launch_bounds__(256)
void conv_silu_k(const u16* __restrict__ xr, const float* __restrict__ cw,
                 const float* __restrict__ cb, u16* __restrict__ xc) {
  const size_t idx = (size_t)blockIdx.x * 256 + threadIdx.x;  // NT*768
  const int d = (int)(idx % DIN);
  const size_t row = idx / DIN;
  const int t = (int)(row & (LSEQ - 1));
  float acc = cb[d];
#pragma unroll
  for (int j = 0; j < 4; ++j) {
    int tt = t - 3 + j;
    if (tt >= 0)
      acc = fmaf(bf2f(xr[(row - 3 + j) * DIN + d]), cw[(d << 2) + j], acc);
  }
  float s = acc / (1.f + __expf(-acc));  // SiLU
  xc[idx] = f2b(s);
}

// xdb[:, :24] (bf16) -> zero-padded 32-col bf16 A operand for dt GEMM
__global__ __launch_bounds__(256)
void pad_dt_k(const u16* __restrict__ xdb, u16* __restrict__ dtA) {
  const size_t idx = (size_t)blockIdx.x * 256 + threadIdx.x;  // NT*32
  const int c = (int)(idx & 31);
  const size_t row = idx >> 5;
  dtA[idx] = (c < 24) ? xdb[row * 152 + c] : (u16)0;
}

// ---------------------------------------------------------------------------
// Selective scan. wave = 4 consecutive d-channels x 16 state-lanes,
// 4 states/lane. dt,xc,B,C all bf16. y out bf16.
// ---------------------------------------------------------------------------
__global__ __launch_bounds__(256)
void scan_k(const u16* __restrict__ dt, const u16* __restrict__ xc,
            const u16* __restrict__ xdb, const float* __restrict__ A_log,
            u16* __restrict__ y) {
  const int wave = (blockIdx.x << 2) + (threadIdx.x >> 6);  // 0..1535
  const int lane = threadIdx.x & 63;
  const int b  = wave / 192;
  const int d0 = (wave - b * 192) << 2;
  const int sg = lane & 15;
  const int d  = d0 + (lane >> 4);
  const int s4 = sg << 2;
  float A0 = -__expf(A_log[(d << 6) + s4 + 0]);
  float A1 = -__expf(A_log[(d << 6) + s4 + 1]);
  float A2 = -__expf(A_log[(d << 6) + s4 + 2]);
  float A3 = -__expf(A_log[(d << 6) + s4 + 3]);
  float h0 = 0.f, h1 = 0.f, h2 = 0.f, h3 = 0.f;
  const size_t row0 = (size_t)b * LSEQ;
  for (int t = 0; t < LSEQ; ++t) {
    const size_t row = row0 + t;
    const float dtv = bf2f(dt[row * DIN + d]);
    const float xv  = bf2f(xc[row * DIN + d]);
    const u16* xrow = xdb + row * 152;
    ushort4 Bv = *(const ushort4*)(xrow + 24 + s4);
    ushort4 Cv = *(const ushort4*)(xrow + 88 + s4);
    const float dtx = dtv * xv;
    h0 = h0 * __expf(dtv * A0) + dtx * bf2f(Bv.x);
    h1 = h1 * __expf(dtv * A1) + dtx * bf2f(Bv.y);
    h2 = h2 * __expf(dtv * A2) + dtx * bf2f(Bv.z);
    h3 = h3 * __expf(dtv * A3) + dtx * bf2f(Bv.w);
    float p = h0 * bf2f(Cv.x) + h1 * bf2f(Cv.y) + h2 * bf2f(Cv.z) + h3 * bf2f(Cv.w);
    p += __shfl_xor(p, 1);
    p += __shfl_xor(p, 2);
    p += __shfl_xor(p, 4);
    p += __shfl_xor(p, 8);
    if (sg == 0) y[row * DIN + d] = f2b(p);
  }
}

// y <- (y + xc*Dp) * silu(z), in place (bf16)
__global__ __launch_bounds__(256)
void gate_k(u16* __restrict__ y, const u16* __restrict__ xc,
            const u16* __restrict__ zb, const float* __restrict__ Dp) {
  const size_t idx = (size_t)blockIdx.x * 256 + threadIdx.x;  // NT*768
  const int d = (int)(idx % DIN);
  const float zz = bf2f(zb[idx]);
  const float sig = zz / (1.f + __expf(-zz));
  const float v = (bf2f(y[idx]) + bf2f(xc[idx]) * Dp[d]) * sig;
  y[idx] = f2b(v);
}

// 3x3 depthwise conv (64x64 grid, pad 1) + exact GELU on a 768-channel half.
// f1 stride 1536; f2h stride 768 holds channels [co, co+768).
__global__ __launch_bounds__(256)
void dw_gelu_k(const u16* __restrict__ f1, const float* __restrict__ ww,
               const float* __restrict__ wb, u16* __restrict__ f2h, int co) {
  const size_t idx = (size_t)blockIdx.x * 256 + threadIdx.x;  // NT*768
  const int cl = (int)(idx % DIN);
  const int c = co + cl;
  const size_t row = idx / DIN;
  const int n = (int)(row & (LSEQ - 1));
  const size_t bb = row >> 12;
  const int i = n >> 6, jj = n & 63;
  float acc = wb[c];
#pragma unroll
  for (int di = -1; di <= 1; ++di) {
    const int ii = i + di;
    if (ii < 0 || ii > 63) continue;
#pragma unroll
    for (int dj = -1; dj <= 1; ++dj) {
      const int j2 = jj + dj;
      if (j2 < 0 || j2 > 63) continue;
      const size_t r2 = (bb << 12) + ((size_t)ii << 6) + j2;
      acc = fmaf(bf2f(f1[r2 * HIDC + c]), ww[c * 9 + (di + 1) * 3 + (dj + 1)], acc);
    }
  }
  const float gel = 0.5f * acc * (1.f + erff(acc * 0.70710678118654752f));
  f2h[idx] = f2b(gel);
}

// ---------------------------------------------------------------------------
extern "C" void kernel_launch(void* const* d_in, const int* in_sizes, int n_in,
                              void* d_out, int out_size, void* d_ws, size_t ws_size,
                              hipStream_t stream) {
  const float* x     = (const float*)d_in[0];
  const float* g1    = (const float*)d_in[3];
  const float* be1   = (const float*)d_in[4];
  const float* W_in  = (const float*)d_in[5];
  const float* convw = (const float*)d_in[6];
  const float* convb = (const float*)d_in[7];
  const float* W_xp  = (const float*)d_in[8];
  const float* W_dt  = (const float*)d_in[9];
  const float* b_dt  = (const float*)d_in[10];
  const float* A_log = (const float*)d_in[11];
  const float* Dp    = (const float*)d_in[12];
  const float* W_out = (const float*)d_in[13];
  const float* g2    = (const float*)d_in[14];
  const float* be2   = (const float*)d_in[15];
  const float* W1    = (const float*)d_in[16];
  const float* b1    = (const float*)d_in[17];
  const float* dww   = (const float*)d_in[18];
  const float* dwb   = (const float*)d_in[19];
  const float* W2    = (const float*)d_in[20];
  const float* b2    = (const float*)d_in[21];
  float* out = (float*)d_out;

  char* ws = (char*)d_ws;
  u16*   r0    = (u16*)(ws + OFF_R0);    // xr / dt / z
  u16*   xc_b  = (u16*)(ws + OFF_XC);
  u16*   xdb_b = (u16*)(ws + OFF_XDB);
  u16*   dtA_b = (u16*)(ws + OFF_DTA);
  u16*   xn_b  = (u16*)(ws + OFF_XN);
  u16*   y_b   = (u16*)(ws + OFF_Y);
  float* x2    = (float*)(ws + OFF_X2);
  u16*   wb    = (u16*)(ws + OFF_WB);
  u16*   f1_b  = r0;                      // spans R0+XC (both dead then)
  u16*   f2h_b = xdb_b;                   // spans XDB..into Y (all dead then)

  // weights -> bf16 (W2 half-split, W_dt padded)
  convert_w_k<<<W_TOTAL / 256, 256, 0, stream>>>(W_in, W_xp, W_out, W1, W2, W_dt, wb);
  // LN1
  ln_k<<<NT / 4, 256, 0, stream>>>(x, g1, be1, xn_b);
  // xr = xn1 @ W_in[:768]^T
  gemm_k<1, 0><<<dim3(12, 512), 256, 0, stream>>>(xn_b, wb + WOF_WIN, r0, nullptr, nullptr, DIN, DIMC);
  // causal dwconv1d + SiLU
  conv_silu_k<<<(NT * DIN) / 256, 256, 0, stream>>>(r0, convw, convb, xc_b);
  // xdb = xc @ W_xproj^T (bf16)
  gemm_k<1, 0><<<dim3(3, 512), 256, 0, stream>>>(xc_b, wb + WOF_WXP, xdb_b, nullptr, nullptr, 152, DIN);
  // dt = softplus(xdb[:, :24] @ W_dt^T + b_dt)  (overwrites xr in R0)
  pad_dt_k<<<(NT * 32) / 256, 256, 0, stream>>>(xdb_b, dtA_b);
  gemm_k<1, 1><<<dim3(12, 512), 256, 0, stream>>>(dtA_b, wb + WOF_WDT, r0, b_dt, nullptr, DIN, 32);
  // selective scan
  scan_k<<<384, 256, 0, stream>>>(r0, xc_b, xdb_b, A_log, y_b);
  // z = xn1 @ W_in[768:]^T  (overwrites dt in R0)
  gemm_k<1, 0><<<dim3(12, 512), 256, 0, stream>>>(xn_b, wb + WOF_WIN + 294912, r0, nullptr, nullptr, DIN, DIMC);
  // gate in place: y <- (y + xc*Dp) * silu(z)
  gate_k<<<(NT * DIN) / 256, 256, 0, stream>>>(y_b, xc_b, r0, Dp);
  // x2 = x + yg @ W_out^T  (f32)
  gemm_k<0, 0><<<dim3(6, 512), 256, 0, stream>>>(y_b, wb + WOF_WOUT, x2, nullptr, x, DIMC, DIN);
  // LN2
  ln_k<<<NT / 4, 256, 0, stream>>>(x2, g2, be2, xn_b);
  // f1 = xn2 @ W1^T + b1  (spans R0+XC)
  gemm_k<1, 0><<<dim3(24, 512), 256, 0, stream>>>(xn_b, wb + WOF_W1, f1_b, b1, nullptr, HIDC, DIMC);
  // half 0: 3x3 depthwise + GELU, then out = x2 + b2 + f2a @ W2a^T
  dw_gelu_k<<<(NT * DIN) / 256, 256, 0, stream>>>(f1_b, dww, dwb, f2h_b, 0);
  gemm_k<0, 0><<<dim3(6, 512), 256, 0, stream>>>(f2h_b, wb + WOF_W2, out, b2, x2, DIMC, DIN);
  // half 1: out += f2b @ W2b^T
  dw_gelu_k<<<(NT * DIN) / 256, 256, 0, stream>>>(f1_b, dww, dwb, f2h_b, DIN);
  gemm_k<0, 0><<<dim3(6, 512), 256, 0, stream>>>(f2h_b, wb + WOF_W2 + 294912, out, nullptr, out, DIMC, DIN);
}

// Round 3
// 2081.187 us; speedup vs baseline: 1.5864x; 1.5864x over previous
//
#include <hip/hip_runtime.h>
#include <math.h>

// ---------------------------------------------------------------------------
// SambaBlock. Round 2: chunked two-pass selective scan (16 chunks x 256 steps)
// to fix the latency-bound serial scan (was 2076 us at 17.7% occupancy).
// Linear recurrence h[t] = exp(dt*A)h[t-1] + dt*x*B  =>  chunk summarized by
// local end-state (scan from 0) and exp(A * sum(dt)) decay; sequential combine
// over 16 chunks is a tiny kernel. Pass 2 re-scans seeded with h_in.
// ---------------------------------------------------------------------------

using u16 = unsigned short;
typedef __bf16 bf8_t __attribute__((ext_vector_type(8)));
typedef float f32x4 __attribute__((ext_vector_type(4)));

#define NT    32768   // B * L
#define LSEQ  4096
#define DIMC  384
#define DIN   768
#define HIDC  1536
#define NCH   16      // scan chunks
#define LCH   256     // steps per chunk

__device__ __forceinline__ float bf2f(u16 u) {
  return __uint_as_float(((unsigned int)u) << 16);
}
__device__ __forceinline__ u16 f2b(float f) {
  unsigned int x = __float_as_uint(f);
  return (u16)((x + 0x7FFFu + ((x >> 16) & 1u)) >> 16);  // RNE
}

// ---------------------------------------------------------------------------
// Workspace layout (bytes). TOTAL = 242,962,432 (~231.7 MiB).
//   R0  [0,          50331648): bf16 NT*768  xr / dt / z ; f1 part 1
//   XC  [50331648,  100663296): bf16 NT*768  xc          ; f1 part 2
//   XDB [100663296, 110624768): bf16 NT*152  xdb         ; f2-half scratch
//   DTA [110624768, 112721920): bf16 NT*32
//   XN  [112721920, 137887744): bf16 NT*384  xn1/xn2
//   Y   [137887744, 188219392): bf16 NT*768  y -> yg (in place)
//   X2  [188219392, 238551040): f32  NT*384  residual; during scan: hend+dtsum
//   WB  [238551040, 242962432): bf16 weights (2205696 elems)
// ---------------------------------------------------------------------------
#define OFF_R0   0ull
#define OFF_XC   50331648ull
#define OFF_XDB  100663296ull
#define OFF_DTA  110624768ull
#define OFF_XN   112721920ull
#define OFF_Y    137887744ull
#define OFF_X2   188219392ull
#define OFF_WB   238551040ull
// scan scratch inside X2 region (x2 written only after scan completes):
//   hend  fp32 [NCH][8][768][64] = 25,165,824 B
//   dtsum fp32 [NCH][8][768]     =    393,216 B
#define OFF_HEND  OFF_X2
#define OFF_DTSUM (OFF_X2 + 25165824ull)
// weight sub-offsets (u16 elements)
#define WOF_WIN  0
#define WOF_WXP  589824
#define WOF_WOUT 706560
#define WOF_W1   1001472
#define WOF_W2   1591296        // stored as [2][384][768] half-split
#define WOF_WDT  2181120        // padded (768,32), cols 24..31 zero
#define W_TOTAL  2205696

// ---------------------------------------------------------------------------
// fp32 -> bf16 weight conversion. W2 permuted to half-split layout.
// ---------------------------------------------------------------------------
__global__ __launch_bounds__(256)
void convert_w_k(const float* __restrict__ Win, const float* __restrict__ Wxp,
                 const float* __restrict__ Wout, const float* __restrict__ W1,
                 const float* __restrict__ W2, const float* __restrict__ Wdt,
                 u16* __restrict__ dst) {
  int i = blockIdx.x * 256 + threadIdx.x;
  float v;
  if (i < WOF_WXP)       v = Win[i];
  else if (i < WOF_WOUT) v = Wxp[i - WOF_WXP];
  else if (i < WOF_W1)   v = Wout[i - WOF_WOUT];
  else if (i < WOF_W2)   v = W1[i - WOF_W1];
  else if (i < WOF_WDT) {
    int j = i - WOF_W2;
    int h = j / 294912; int rem = j - h * 294912;
    int r = rem / 768;  int k = rem - r * 768;
    v = W2[r * 1536 + h * 768 + k];
  } else {
    int j = i - WOF_WDT; int c = j & 31; int r = j >> 5;
    v = (c < 24) ? Wdt[r * 24 + c] : 0.f;
  }
  dst[i] = f2b(v);
}

// ---------------------------------------------------------------------------
// LayerNorm over rows of 384, one wave per row, bf16 output.
// ---------------------------------------------------------------------------
__global__ __launch_bounds__(256)
void ln_k(const float* __restrict__ x, const float* __restrict__ g,
          const float* __restrict__ b, u16* __restrict__ out) {
  const int row  = (blockIdx.x << 2) + (threadIdx.x >> 6);
  const int lane = threadIdx.x & 63;
  const float* xr = x + (size_t)row * DIMC;
  float v[6]; float s = 0.f;
#pragma unroll
  for (int j = 0; j < 6; ++j) { v[j] = xr[lane + (j << 6)]; s += v[j]; }
#pragma unroll
  for (int m = 1; m < 64; m <<= 1) s += __shfl_xor(s, m);
  const float mu = s * (1.f / DIMC);
  float q = 0.f;
#pragma unroll
  for (int j = 0; j < 6; ++j) { float dv = v[j] - mu; q += dv * dv; }
#pragma unroll
  for (int m = 1; m < 64; m <<= 1) q += __shfl_xor(q, m);
  const float rs = rsqrtf(q * (1.f / DIMC) + 1e-5f);
  u16* orow = out + (size_t)row * DIMC;
#pragma unroll
  for (int j = 0; j < 6; ++j) {
    int c = lane + (j << 6);
    orow[c] = f2b((v[j] - mu) * rs * g[c] + b[c]);
  }
}

// ---------------------------------------------------------------------------
// bf16 MFMA GEMM: C[M,N] = A[M,K] @ W[N,K]^T (+bias +resid, opt softplus).
// Block 256 = 4 waves, tile 64x64, BK=32.
// ---------------------------------------------------------------------------
template<int OUT_BF16, int ACT>
__global__ __launch_bounds__(256)
void gemm_k(const u16* __restrict__ A, const u16* __restrict__ Bw,
            void* __restrict__ Cout, const float* __restrict__ bias,
            const float* __restrict__ resid, int N, int K) {
  __shared__ __align__(16) u16 As[64][40];
  __shared__ __align__(16) u16 Bs[64][40];
  const int tid  = threadIdx.x;
  const int lane = tid & 63;
  const int wave = tid >> 6;
  const int bn = blockIdx.x << 6;
  const int bm = blockIdx.y << 6;
  const int srow = tid >> 2;
  const int scol = (tid & 3) << 3;
  const int wm = (wave >> 1) << 5;
  const int wn = (wave & 1) << 5;
  const int fr = lane & 15;
  const int fq = lane >> 4;
  f32x4 acc[2][2] = {};
  for (int k0 = 0; k0 < K; k0 += 32) {
    uint4 av = *(const uint4*)(A + (size_t)(bm + srow) * K + k0 + scol);
    uint4 bv = make_uint4(0u, 0u, 0u, 0u);
    if (bn + srow < N)
      bv = *(const uint4*)(Bw + (size_t)(bn + srow) * K + k0 + scol);
    *(uint4*)&As[srow][scol] = av;
    *(uint4*)&Bs[srow][scol] = bv;
    __syncthreads();
    bf8_t a0 = *(const bf8_t*)&As[wm + fr][fq << 3];
    bf8_t a1 = *(const bf8_t*)&As[wm + 16 + fr][fq << 3];
    bf8_t b0 = *(const bf8_t*)&Bs[wn + fr][fq << 3];
    bf8_t b1 = *(const bf8_t*)&Bs[wn + 16 + fr][fq << 3];
    acc[0][0] = __builtin_amdgcn_mfma_f32_16x16x32_bf16(a0, b0, acc[0][0], 0, 0, 0);
    acc[0][1] = __builtin_amdgcn_mfma_f32_16x16x32_bf16(a0, b1, acc[0][1], 0, 0, 0);
    acc[1][0] = __builtin_amdgcn_mfma_f32_16x16x32_bf16(a1, b0, acc[1][0], 0, 0, 0);
    acc[1][1] = __builtin_amdgcn_mfma_f32_16x16x32_bf16(a1, b1, acc[1][1], 0, 0, 0);
    __syncthreads();
  }
#pragma unroll
  for (int i = 0; i < 2; ++i) {
#pragma unroll
    for (int j = 0; j < 2; ++j) {
      const int col = bn + wn + (j << 4) + fr;
      if (col >= N) continue;
      const float bv = bias ? bias[col] : 0.f;
#pragma unroll
      for (int r = 0; r < 4; ++r) {
        const int row = bm + wm + (i << 4) + (fq << 2) + r;
        float v = acc[i][j][r] + bv;
        if (resid) v += resid[(size_t)row * N + col];
        if (ACT == 1) v = (v > 20.f) ? v : log1pf(__expf(v));  // softplus
        if (OUT_BF16) ((u16*)Cout)[(size_t)row * N + col] = f2b(v);
        else          ((float*)Cout)[(size_t)row * N + col] = v;
      }
    }
  }
}

// ---------------------------------------------------------------------------
// Causal depthwise conv1d (k=4, left pad 3) + SiLU.
// ---------------------------------------------------------------------------
__global__ __launch_bounds__(256)
void conv_silu_k(const u16* __restrict__ xr, const float* __restrict__ cw,
                 const float* __restrict__ cb, u16* __restrict__ xc) {
  const size_t idx = (size_t)blockIdx.x * 256 + threadIdx.x;  // NT*768
  const int d = (int)(idx % DIN);
  const size_t row = idx / DIN;
  const int t = (int)(row & (LSEQ - 1));
  float acc = cb[d];
#pragma unroll
  for (int j = 0; j < 4; ++j) {
    int tt = t - 3 + j;
    if (tt >= 0)
      acc = fmaf(bf2f(xr[(row - 3 + j) * DIN + d]), cw[(d << 2) + j], acc);
  }
  float s = acc / (1.f + __expf(-acc));  // SiLU
  xc[idx] = f2b(s);
}

// xdb[:, :24] (bf16) -> zero-padded 32-col bf16 A operand for dt GEMM
__global__ __launch_bounds__(256)
void pad_dt_k(const u16* __restrict__ xdb, u16* __restrict__ dtA) {
  const size_t idx = (size_t)blockIdx.x * 256 + threadIdx.x;  // NT*32
  const int c = (int)(idx & 31);
  const size_t row = idx >> 5;
  dtA[idx] = (c < 24) ? xdb[row * 152 + c] : (u16)0;
}

// ---------------------------------------------------------------------------
// Chunked scan. wave = (chunk, batch, 4 d-channels) x 16 state-lanes.
// Pass 1: local scan from h=0 over LCH steps; emit h_end (float4/lane) and
// per-d sum of dt (sg==0 lanes).
// ---------------------------------------------------------------------------
__global__ __launch_bounds__(256)
void scan_p1_k(const u16* __restrict__ dt, const u16* __restrict__ xc,
               const u16* __restrict__ xdb, const float* __restrict__ A_log,
               float* __restrict__ hend, float* __restrict__ dtsum) {
  const int wave = (blockIdx.x << 2) + (threadIdx.x >> 6);  // 0..NCH*1536-1
  const int lane = threadIdx.x & 63;
  const int c   = wave >> 10;          // wave / 1536 would be wrong; do below
  // careful: 1536 not a power of two — compute properly:
  const int cc  = wave / 1536;
  const int rem = wave - cc * 1536;
  (void)c;
  const int b  = rem / 192;
  const int d0 = (rem - b * 192) << 2;
  const int sg = lane & 15;
  const int d  = d0 + (lane >> 4);
  const int s4 = sg << 2;
  const float A0 = -__expf(A_log[(d << 6) + s4 + 0]);
  const float A1 = -__expf(A_log[(d << 6) + s4 + 1]);
  const float A2 = -__expf(A_log[(d << 6) + s4 + 2]);
  const float A3 = -__expf(A_log[(d << 6) + s4 + 3]);
  float h0 = 0.f, h1 = 0.f, h2 = 0.f, h3 = 0.f, ds = 0.f;
  const size_t row0 = (size_t)b * LSEQ + (size_t)cc * LCH;
  for (int t = 0; t < LCH; ++t) {
    const size_t row = row0 + t;
    const float dtv = bf2f(dt[row * DIN + d]);
    const float xv  = bf2f(xc[row * DIN + d]);
    ushort4 Bv = *(const ushort4*)(xdb + row * 152 + 24 + s4);
    const float dtx = dtv * xv;
    h0 = h0 * __expf(dtv * A0) + dtx * bf2f(Bv.x);
    h1 = h1 * __expf(dtv * A1) + dtx * bf2f(Bv.y);
    h2 = h2 * __expf(dtv * A2) + dtx * bf2f(Bv.z);
    h3 = h3 * __expf(dtv * A3) + dtx * bf2f(Bv.w);
    ds += dtv;
  }
  const size_t base = ((size_t)((cc << 3) + b) * DIN + d) * 64 + s4;
  *(float4*)(hend + base) = make_float4(h0, h1, h2, h3);
  if (sg == 0) dtsum[((cc << 3) + b) * DIN + d] = ds;
}

// Sequential combine over chunks: h_in[c] = exp(A*dtsum[c-1])*h_in[c-1] +
// hend[c-1], written in-place over hend. 393216 threads, 16 iters each.
__global__ __launch_bounds__(256)
void scan_comb_k(const float* __restrict__ A_log,
                 const float* __restrict__ dtsum, float* __restrict__ hend) {
  const int idx = blockIdx.x * 256 + threadIdx.x;  // (b*768+d)*64+s
  const int s  = idx & 63;
  const int bd = idx >> 6;
  const int d  = bd % DIN;
  const float A = -__expf(A_log[(d << 6) + s]);
  float h = 0.f;
#pragma unroll
  for (int c = 0; c < NCH; ++c) {
    float* p = hend + (size_t)c * 393216 + idx;
    const float e = *p;
    *p = h;
    h = h * __expf(A * dtsum[c * 6144 + bd]) + e;
  }
}

// Pass 2: scan seeded with h_in, produce y (bf16).
__global__ __launch_bounds__(256)
void scan_p2_k(const u16* __restrict__ dt, const u16* __restrict__ xc,
               const u16* __restrict__ xdb, const float* __restrict__ A_log,
               const float* __restrict__ hin, u16* __restrict__ y) {
  const int wave = (blockIdx.x << 2) + (threadIdx.x >> 6);
  const int lane = threadIdx.x & 63;
  const int cc  = wave / 1536;
  const int rem = wave - cc * 1536;
  const int b  = rem / 192;
  const int d0 = (rem - b * 192) << 2;
  const int sg = lane & 15;
  const int d  = d0 + (lane >> 4);
  const int s4 = sg << 2;
  const float A0 = -__expf(A_log[(d << 6) + s4 + 0]);
  const float A1 = -__expf(A_log[(d << 6) + s4 + 1]);
  const float A2 = -__expf(A_log[(d << 6) + s4 + 2]);
  const float A3 = -__expf(A_log[(d << 6) + s4 + 3]);
  const size_t base = ((size_t)((cc << 3) + b) * DIN + d) * 64 + s4;
  const float4 hv = *(const float4*)(hin + base);
  float h0 = hv.x, h1 = hv.y, h2 = hv.z, h3 = hv.w;
  const size_t row0 = (size_t)b * LSEQ + (size_t)cc * LCH;
  for (int t = 0; t < LCH; ++t) {
    const size_t row = row0 + t;
    const float dtv = bf2f(dt[row * DIN + d]);
    const float xv  = bf2f(xc[row * DIN + d]);
    const u16* xrow = xdb + row * 152;
    ushort4 Bv = *(const ushort4*)(xrow + 24 + s4);
    ushort4 Cv = *(const ushort4*)(xrow + 88 + s4);
    const float dtx = dtv * xv;
    h0 = h0 * __expf(dtv * A0) + dtx * bf2f(Bv.x);
    h1 = h1 * __expf(dtv * A1) + dtx * bf2f(Bv.y);
    h2 = h2 * __expf(dtv * A2) + dtx * bf2f(Bv.z);
    h3 = h3 * __expf(dtv * A3) + dtx * bf2f(Bv.w);
    float p = h0 * bf2f(Cv.x) + h1 * bf2f(Cv.y) + h2 * bf2f(Cv.z) + h3 * bf2f(Cv.w);
    p += __shfl_xor(p, 1);
    p += __shfl_xor(p, 2);
    p += __shfl_xor(p, 4);
    p += __shfl_xor(p, 8);
    if (sg == 0) y[row * DIN + d] = f2b(p);
  }
}

// y <- (y + xc*Dp) * silu(z), in place (bf16)
__global__ __launch_bounds__(256)
void gate_k(u16* __restrict__ y, const u16* __restrict__ xc,
            const u16* __restrict__ zb, const float* __restrict__ Dp) {
  const size_t idx = (size_t)blockIdx.x * 256 + threadIdx.x;  // NT*768
  const int d = (int)(idx % DIN);
  const float zz = bf2f(zb[idx]);
  const float sig = zz / (1.f + __expf(-zz));
  const float v = (bf2f(y[idx]) + bf2f(xc[idx]) * Dp[d]) * sig;
  y[idx] = f2b(v);
}

// 3x3 depthwise conv (64x64 grid, pad 1) + exact GELU on a 768-channel half.
__global__ __launch_bounds__(256)
void dw_gelu_k(const u16* __restrict__ f1, const float* __restrict__ ww,
               const float* __restrict__ wb, u16* __restrict__ f2h, int co) {
  const size_t idx = (size_t)blockIdx.x * 256 + threadIdx.x;  // NT*768
  const int cl = (int)(idx % DIN);
  const int c = co + cl;
  const size_t row = idx / DIN;
  const int n = (int)(row & (LSEQ - 1));
  const size_t bb = row >> 12;
  const int i = n >> 6, jj = n & 63;
  float acc = wb[c];
#pragma unroll
  for (int di = -1; di <= 1; ++di) {
    const int ii = i + di;
    if (ii < 0 || ii > 63) continue;
#pragma unroll
    for (int dj = -1; dj <= 1; ++dj) {
      const int j2 = jj + dj;
      if (j2 < 0 || j2 > 63) continue;
      const size_t r2 = (bb << 12) + ((size_t)ii << 6) + j2;
      acc = fmaf(bf2f(f1[r2 * HIDC + c]), ww[c * 9 + (di + 1) * 3 + (dj + 1)], acc);
    }
  }
  const float gel = 0.5f * acc * (1.f + erff(acc * 0.70710678118654752f));
  f2h[idx] = f2b(gel);
}

// ---------------------------------------------------------------------------
extern "C" void kernel_launch(void* const* d_in, const int* in_sizes, int n_in,
                              void* d_out, int out_size, void* d_ws, size_t ws_size,
                              hipStream_t stream) {
  const float* x     = (const float*)d_in[0];
  const float* g1    = (const float*)d_in[3];
  const float* be1   = (const float*)d_in[4];
  const float* W_in  = (const float*)d_in[5];
  const float* convw = (const float*)d_in[6];
  const float* convb = (const float*)d_in[7];
  const float* W_xp  = (const float*)d_in[8];
  const float* W_dt  = (const float*)d_in[9];
  const float* b_dt  = (const float*)d_in[10];
  const float* A_log = (const float*)d_in[11];
  const float* Dp    = (const float*)d_in[12];
  const float* W_out = (const float*)d_in[13];
  const float* g2    = (const float*)d_in[14];
  const float* be2   = (const float*)d_in[15];
  const float* W1    = (const float*)d_in[16];
  const float* b1    = (const float*)d_in[17];
  const float* dww   = (const float*)d_in[18];
  const float* dwb   = (const float*)d_in[19];
  const float* W2    = (const float*)d_in[20];
  const float* b2    = (const float*)d_in[21];
  float* out = (float*)d_out;

  char* ws = (char*)d_ws;
  u16*   r0    = (u16*)(ws + OFF_R0);    // xr / dt / z
  u16*   xc_b  = (u16*)(ws + OFF_XC);
  u16*   xdb_b = (u16*)(ws + OFF_XDB);
  u16*   dtA_b = (u16*)(ws + OFF_DTA);
  u16*   xn_b  = (u16*)(ws + OFF_XN);
  u16*   y_b   = (u16*)(ws + OFF_Y);
  float* x2    = (float*)(ws + OFF_X2);
  float* hend  = (float*)(ws + OFF_HEND);
  float* dtsum = (float*)(ws + OFF_DTSUM);
  u16*   wb    = (u16*)(ws + OFF_WB);
  u16*   f1_b  = r0;                      // spans R0+XC (both dead then)
  u16*   f2h_b = xdb_b;                   // spans XDB.. (all dead then)

  // weights -> bf16 (W2 half-split, W_dt padded)
  convert_w_k<<<W_TOTAL / 256, 256, 0, stream>>>(W_in, W_xp, W_out, W1, W2, W_dt, wb);
  // LN1
  ln_k<<<NT / 4, 256, 0, stream>>>(x, g1, be1, xn_b);
  // xr = xn1 @ W_in[:768]^T
  gemm_k<1, 0><<<dim3(12, 512), 256, 0, stream>>>(xn_b, wb + WOF_WIN, r0, nullptr, nullptr, DIN, DIMC);
  // causal dwconv1d + SiLU
  conv_silu_k<<<(NT * DIN) / 256, 256, 0, stream>>>(r0, convw, convb, xc_b);
  // xdb = xc @ W_xproj^T (bf16)
  gemm_k<1, 0><<<dim3(3, 512), 256, 0, stream>>>(xc_b, wb + WOF_WXP, xdb_b, nullptr, nullptr, 152, DIN);
  // dt = softplus(xdb[:, :24] @ W_dt^T + b_dt)  (overwrites xr in R0)
  pad_dt_k<<<(NT * 32) / 256, 256, 0, stream>>>(xdb_b, dtA_b);
  gemm_k<1, 1><<<dim3(12, 512), 256, 0, stream>>>(dtA_b, wb + WOF_WDT, r0, b_dt, nullptr, DIN, 32);
  // chunked selective scan: pass1 -> combine -> pass2
  scan_p1_k<<<(NCH * 1536) / 4, 256, 0, stream>>>(r0, xc_b, xdb_b, A_log, hend, dtsum);
  scan_comb_k<<<393216 / 256, 256, 0, stream>>>(A_log, dtsum, hend);
  scan_p2_k<<<(NCH * 1536) / 4, 256, 0, stream>>>(r0, xc_b, xdb_b, A_log, hend, y_b);
  // z = xn1 @ W_in[768:]^T  (overwrites dt in R0)
  gemm_k<1, 0><<<dim3(12, 512), 256, 0, stream>>>(xn_b, wb + WOF_WIN + 294912, r0, nullptr, nullptr, DIN, DIMC);
  // gate in place: y <- (y + xc*Dp) * silu(z)
  gate_k<<<(NT * DIN) / 256, 256, 0, stream>>>(y_b, xc_b, r0, Dp);
  // x2 = x + yg @ W_out^T  (f32)
  gemm_k<0, 0><<<dim3(6, 512), 256, 0, stream>>>(y_b, wb + WOF_WOUT, x2, nullptr, x, DIMC, DIN);
  // LN2
  ln_k<<<NT / 4, 256, 0, stream>>>(x2, g2, be2, xn_b);
  // f1 = xn2 @ W1^T + b1  (spans R0+XC)
  gemm_k<1, 0><<<dim3(24, 512), 256, 0, stream>>>(xn_b, wb + WOF_W1, f1_b, b1, nullptr, HIDC, DIMC);
  // half 0: 3x3 depthwise + GELU, then out = x2 + b2 + f2a @ W2a^T
  dw_gelu_k<<<(NT * DIN) / 256, 256, 0, stream>>>(f1_b, dww, dwb, f2h_b, 0);
  gemm_k<0, 0><<<dim3(6, 512), 256, 0, stream>>>(f2h_b, wb + WOF_W2, out, b2, x2, DIMC, DIN);
  // half 1: out += f2b @ W2b^T
  dw_gelu_k<<<(NT * DIN) / 256, 256, 0, stream>>>(f1_b, dww, dwb, f2h_b, DIN);
  gemm_k<0, 0><<<dim3(6, 512), 256, 0, stream>>>(f2h_b, wb + WOF_W2 + 294912, out, nullptr, out, DIMC, DIN);
}

// Round 4
// 1982.417 us; speedup vs baseline: 1.6654x; 1.0498x over previous
//
#include <hip/hip_runtime.h>
#include <math.h>

// ---------------------------------------------------------------------------
// SambaBlock. Round 3:
//  (a) scan instruction diet: exp2 with pre-scaled A, pointer bumping,
//      unroll-4 (scan pair was 1050us, VALU-issue-bound at ~200 cyc/step).
//  (b) m97-recipe GEMM (128x128 tile, BK=32, global_load_lds 16B, 4x4 frags)
//      for all N in {384,768,1536} GEMMs; old 64^2 kernel kept for N=152.
// ---------------------------------------------------------------------------

using u16 = unsigned short;
typedef __bf16 bf8_t __attribute__((ext_vector_type(8)));
typedef float f32x4 __attribute__((ext_vector_type(4)));

#define NT    32768   // B * L
#define LSEQ  4096
#define DIMC  384
#define DIN   768
#define HIDC  1536
#define NCH   16      // scan chunks
#define LCH   256     // steps per chunk

__device__ __forceinline__ float bf2f(u16 u) {
  return __uint_as_float(((unsigned int)u) << 16);
}
__device__ __forceinline__ u16 f2b(float f) {
  unsigned int x = __float_as_uint(f);
  return (u16)((x + 0x7FFFu + ((x >> 16) & 1u)) >> 16);  // RNE
}

// async 16B global->LDS (wave-uniform LDS base + lane*16 ordering)
#define GLDS16(gp, lp)                                                      \
  __builtin_amdgcn_global_load_lds(                                         \
      (const __attribute__((address_space(1))) unsigned int*)(gp),          \
      (__attribute__((address_space(3))) unsigned int*)(lp), 16, 0, 0)

// ---------------------------------------------------------------------------
// Workspace layout (bytes). TOTAL = 242,962,432 (~231.7 MiB).  (unchanged)
// ---------------------------------------------------------------------------
#define OFF_R0   0ull
#define OFF_XC   50331648ull
#define OFF_XDB  100663296ull
#define OFF_DTA  110624768ull
#define OFF_XN   112721920ull
#define OFF_Y    137887744ull
#define OFF_X2   188219392ull
#define OFF_WB   238551040ull
#define OFF_HEND  OFF_X2
#define OFF_DTSUM (OFF_X2 + 25165824ull)
// weight sub-offsets (u16 elements)
#define WOF_WIN  0
#define WOF_WXP  589824
#define WOF_WOUT 706560
#define WOF_W1   1001472
#define WOF_W2   1591296        // stored as [2][384][768] half-split
#define WOF_WDT  2181120        // padded (768,32), cols 24..31 zero
#define W_TOTAL  2205696

// ---------------------------------------------------------------------------
// fp32 -> bf16 weight conversion. W2 permuted to half-split layout.
// ---------------------------------------------------------------------------
__global__ __launch_bounds__(256)
void convert_w_k(const float* __restrict__ Win, const float* __restrict__ Wxp,
                 const float* __restrict__ Wout, const float* __restrict__ W1,
                 const float* __restrict__ W2, const float* __restrict__ Wdt,
                 u16* __restrict__ dst) {
  int i = blockIdx.x * 256 + threadIdx.x;
  float v;
  if (i < WOF_WXP)       v = Win[i];
  else if (i < WOF_WOUT) v = Wxp[i - WOF_WXP];
  else if (i < WOF_W1)   v = Wout[i - WOF_WOUT];
  else if (i < WOF_W2)   v = W1[i - WOF_W1];
  else if (i < WOF_WDT) {
    int j = i - WOF_W2;
    int h = j / 294912; int rem = j - h * 294912;
    int r = rem / 768;  int k = rem - r * 768;
    v = W2[r * 1536 + h * 768 + k];
  } else {
    int j = i - WOF_WDT; int c = j & 31; int r = j >> 5;
    v = (c < 24) ? Wdt[r * 24 + c] : 0.f;
  }
  dst[i] = f2b(v);
}

// ---------------------------------------------------------------------------
// LayerNorm over rows of 384, one wave per row, bf16 output.
// ---------------------------------------------------------------------------
__global__ __launch_bounds__(256)
void ln_k(const float* __restrict__ x, const float* __restrict__ g,
          const float* __restrict__ b, u16* __restrict__ out) {
  const int row  = (blockIdx.x << 2) + (threadIdx.x >> 6);
  const int lane = threadIdx.x & 63;
  const float* xr = x + (size_t)row * DIMC;
  float v[6]; float s = 0.f;
#pragma unroll
  for (int j = 0; j < 6; ++j) { v[j] = xr[lane + (j << 6)]; s += v[j]; }
#pragma unroll
  for (int m = 1; m < 64; m <<= 1) s += __shfl_xor(s, m);
  const float mu = s * (1.f / DIMC);
  float q = 0.f;
#pragma unroll
  for (int j = 0; j < 6; ++j) { float dv = v[j] - mu; q += dv * dv; }
#pragma unroll
  for (int m = 1; m < 64; m <<= 1) q += __shfl_xor(q, m);
  const float rs = rsqrtf(q * (1.f / DIMC) + 1e-5f);
  u16* orow = out + (size_t)row * DIMC;
#pragma unroll
  for (int j = 0; j < 6; ++j) {
    int c = lane + (j << 6);
    orow[c] = f2b((v[j] - mu) * rs * g[c] + b[c]);
  }
}

// ---------------------------------------------------------------------------
// Old 64x64 GEMM (kept only for N=152 xdb projection). C = A @ W^T.
// ---------------------------------------------------------------------------
template<int OUT_BF16, int ACT>
__global__ __launch_bounds__(256)
void gemm_k(const u16* __restrict__ A, const u16* __restrict__ Bw,
            void* __restrict__ Cout, const float* __restrict__ bias,
            const float* __restrict__ resid, int N, int K) {
  __shared__ __align__(16) u16 As[64][40];
  __shared__ __align__(16) u16 Bs[64][40];
  const int tid  = threadIdx.x;
  const int lane = tid & 63;
  const int wave = tid >> 6;
  const int bn = blockIdx.x << 6;
  const int bm = blockIdx.y << 6;
  const int srow = tid >> 2;
  const int scol = (tid & 3) << 3;
  const int wm = (wave >> 1) << 5;
  const int wn = (wave & 1) << 5;
  const int fr = lane & 15;
  const int fq = lane >> 4;
  f32x4 acc[2][2] = {};
  for (int k0 = 0; k0 < K; k0 += 32) {
    uint4 av = *(const uint4*)(A + (size_t)(bm + srow) * K + k0 + scol);
    uint4 bv = make_uint4(0u, 0u, 0u, 0u);
    if (bn + srow < N)
      bv = *(const uint4*)(Bw + (size_t)(bn + srow) * K + k0 + scol);
    *(uint4*)&As[srow][scol] = av;
    *(uint4*)&Bs[srow][scol] = bv;
    __syncthreads();
    bf8_t a0 = *(const bf8_t*)&As[wm + fr][fq << 3];
    bf8_t a1 = *(const bf8_t*)&As[wm + 16 + fr][fq << 3];
    bf8_t b0 = *(const bf8_t*)&Bs[wn + fr][fq << 3];
    bf8_t b1 = *(const bf8_t*)&Bs[wn + 16 + fr][fq << 3];
    acc[0][0] = __builtin_amdgcn_mfma_f32_16x16x32_bf16(a0, b0, acc[0][0], 0, 0, 0);
    acc[0][1] = __builtin_amdgcn_mfma_f32_16x16x32_bf16(a0, b1, acc[0][1], 0, 0, 0);
    acc[1][0] = __builtin_amdgcn_mfma_f32_16x16x32_bf16(a1, b0, acc[1][0], 0, 0, 0);
    acc[1][1] = __builtin_amdgcn_mfma_f32_16x16x32_bf16(a1, b1, acc[1][1], 0, 0, 0);
    __syncthreads();
  }
#pragma unroll
  for (int i = 0; i < 2; ++i) {
#pragma unroll
    for (int j = 0; j < 2; ++j) {
      const int col = bn + wn + (j << 4) + fr;
      if (col >= N) continue;
      const float bv = bias ? bias[col] : 0.f;
#pragma unroll
      for (int r = 0; r < 4; ++r) {
        const int row = bm + wm + (i << 4) + (fq << 2) + r;
        float v = acc[i][j][r] + bv;
        if (resid) v += resid[(size_t)row * N + col];
        if (ACT == 1) v = (v > 20.f) ? v : log1pf(__expf(v));
        if (OUT_BF16) ((u16*)Cout)[(size_t)row * N + col] = f2b(v);
        else          ((float*)Cout)[(size_t)row * N + col] = v;
      }
    }
  }
}

// ---------------------------------------------------------------------------
// m97-recipe GEMM: 128x128 tile, BK=32, global_load_lds 16B staging,
// 4 waves x (64x64 per wave) = 4x4 frags of 16x16x32. Requires N%128==0,
// K%32==0, M%128==0. C[M,N] = A[M,K] @ W[N,K]^T (+bias +resid +opt softplus).
// LDS unpadded [128][32] bf16 (rows 64B); staging order = lane-contiguous.
// ---------------------------------------------------------------------------
template<int OUT_BF16, int ACT>
__global__ __launch_bounds__(256)
void gemm128_k(const u16* __restrict__ A, const u16* __restrict__ Bw,
               void* __restrict__ Cout, const float* __restrict__ bias,
               const float* __restrict__ resid, int N, int K) {
  __shared__ __align__(16) u16 As[4096];   // 128 x 32
  __shared__ __align__(16) u16 Bs[4096];
  const int tid  = threadIdx.x;
  const int lane = tid & 63;
  const int wave = tid >> 6;
  const int bm = blockIdx.y << 7;
  const int bn = blockIdx.x << 7;
  const int wm = (wave >> 1) << 6;
  const int wn = (wave & 1) << 6;
  const int fr = lane & 15;
  const int fq = lane >> 4;
  // staging: chunk = 16B unit; chunk c -> row c>>2, col8 (c&3)*8
  const int ch0 = tid;
  const int ch1 = tid + 256;
  const int r0c = ch0 >> 2, c0c = (ch0 & 3) << 3;
  const int r1c = ch1 >> 2, c1c = (ch1 & 3) << 3;
  f32x4 acc[4][4] = {};
  for (int k0 = 0; k0 < K; k0 += 32) {
    GLDS16(A + (size_t)(bm + r0c) * K + k0 + c0c, As + ch0 * 8);
    GLDS16(A + (size_t)(bm + r1c) * K + k0 + c1c, As + ch1 * 8);
    GLDS16(Bw + (size_t)(bn + r0c) * K + k0 + c0c, Bs + ch0 * 8);
    GLDS16(Bw + (size_t)(bn + r1c) * K + k0 + c1c, Bs + ch1 * 8);
    __syncthreads();   // compiler emits vmcnt(0) drain before barrier
    bf8_t a[4], b[4];
#pragma unroll
    for (int i = 0; i < 4; ++i)
      a[i] = *(const bf8_t*)&As[(wm + (i << 4) + fr) * 32 + (fq << 3)];
#pragma unroll
    for (int j = 0; j < 4; ++j)
      b[j] = *(const bf8_t*)&Bs[(wn + (j << 4) + fr) * 32 + (fq << 3)];
#pragma unroll
    for (int i = 0; i < 4; ++i)
#pragma unroll
      for (int j = 0; j < 4; ++j)
        acc[i][j] = __builtin_amdgcn_mfma_f32_16x16x32_bf16(a[i], b[j], acc[i][j], 0, 0, 0);
    __syncthreads();
  }
#pragma unroll
  for (int i = 0; i < 4; ++i) {
#pragma unroll
    for (int j = 0; j < 4; ++j) {
      const int col = bn + wn + (j << 4) + fr;
      const float bv = bias ? bias[col] : 0.f;
#pragma unroll
      for (int r = 0; r < 4; ++r) {
        const int row = bm + wm + (i << 4) + (fq << 2) + r;
        float v = acc[i][j][r] + bv;
        if (resid) v += resid[(size_t)row * N + col];
        if (ACT == 1) v = (v > 20.f) ? v : log1pf(__expf(v));
        if (OUT_BF16) ((u16*)Cout)[(size_t)row * N + col] = f2b(v);
        else          ((float*)Cout)[(size_t)row * N + col] = v;
      }
    }
  }
}

// ---------------------------------------------------------------------------
// Causal depthwise conv1d (k=4, left pad 3) + SiLU.
// ---------------------------------------------------------------------------
__global__ __launch_bounds__(256)
void conv_silu_k(const u16* __restrict__ xr, const float* __restrict__ cw,
                 const float* __restrict__ cb, u16* __restrict__ xc) {
  const size_t idx = (size_t)blockIdx.x * 256 + threadIdx.x;  // NT*768
  const int d = (int)(idx % DIN);
  const size_t row = idx / DIN;
  const int t = (int)(row & (LSEQ - 1));
  float acc = cb[d];
#pragma unroll
  for (int j = 0; j < 4; ++j) {
    int tt = t - 3 + j;
    if (tt >= 0)
      acc = fmaf(bf2f(xr[(row - 3 + j) * DIN + d]), cw[(d << 2) + j], acc);
  }
  float s = acc / (1.f + __expf(-acc));  // SiLU
  xc[idx] = f2b(s);
}

// xdb[:, :24] (bf16) -> zero-padded 32-col bf16 A operand for dt GEMM
__global__ __launch_bounds__(256)
void pad_dt_k(const u16* __restrict__ xdb, u16* __restrict__ dtA) {
  const size_t idx = (size_t)blockIdx.x * 256 + threadIdx.x;  // NT*32
  const int c = (int)(idx & 31);
  const size_t row = idx >> 5;
  dtA[idx] = (c < 24) ? xdb[row * 152 + c] : (u16)0;
}

// ---------------------------------------------------------------------------
// Chunked scan, instruction-dieted: A pre-scaled by log2e -> raw v_exp_f32,
// pointer bumping, unroll 4 (reduction chain has no feedback into h).
// ---------------------------------------------------------------------------
#define L2E 1.4426950408889634f

__global__ __launch_bounds__(256)
void scan_p1_k(const u16* __restrict__ dt, const u16* __restrict__ xc,
               const u16* __restrict__ xdb, const float* __restrict__ A_log,
               float* __restrict__ hend, float* __restrict__ dtsum) {
  const int wave = (blockIdx.x << 2) + (threadIdx.x >> 6);  // 0..NCH*1536-1
  const int lane = threadIdx.x & 63;
  const int cc  = wave / 1536;
  const int rem = wave - cc * 1536;
  const int b  = rem / 192;
  const int d0 = (rem - b * 192) << 2;
  const int sg = lane & 15;
  const int d  = d0 + (lane >> 4);
  const int s4 = sg << 2;
  const float A0 = -__expf(A_log[(d << 6) + s4 + 0]) * L2E;
  const float A1 = -__expf(A_log[(d << 6) + s4 + 1]) * L2E;
  const float A2 = -__expf(A_log[(d << 6) + s4 + 2]) * L2E;
  const float A3 = -__expf(A_log[(d << 6) + s4 + 3]) * L2E;
  float h0 = 0.f, h1 = 0.f, h2 = 0.f, h3 = 0.f, ds = 0.f;
  const size_t row0 = (size_t)b * LSEQ + (size_t)cc * LCH;
  const u16* pdt = dt + row0 * DIN + d;
  const u16* pxc = xc + row0 * DIN + d;
  const u16* pB  = xdb + row0 * 152 + 24 + s4;
#pragma unroll 4
  for (int t = 0; t < LCH; ++t) {
    const float dtv = bf2f(*pdt);
    const float xv  = bf2f(*pxc);
    const ushort4 Bv = *(const ushort4*)pB;
    pdt += DIN; pxc += DIN; pB += 152;
    const float dtx = dtv * xv;
    h0 = h0 * __builtin_amdgcn_exp2f(dtv * A0) + dtx * bf2f(Bv.x);
    h1 = h1 * __builtin_amdgcn_exp2f(dtv * A1) + dtx * bf2f(Bv.y);
    h2 = h2 * __builtin_amdgcn_exp2f(dtv * A2) + dtx * bf2f(Bv.z);
    h3 = h3 * __builtin_amdgcn_exp2f(dtv * A3) + dtx * bf2f(Bv.w);
    ds += dtv;
  }
  const size_t base = ((size_t)((cc << 3) + b) * DIN + d) * 64 + s4;
  *(float4*)(hend + base) = make_float4(h0, h1, h2, h3);
  if (sg == 0) dtsum[((cc << 3) + b) * DIN + d] = ds;
}

// Sequential combine: h_in[c] = exp(A*dtsum[c-1])*h_in[c-1] + hend[c-1],
// in-place over hend.
__global__ __launch_bounds__(256)
void scan_comb_k(const float* __restrict__ A_log,
                 const float* __restrict__ dtsum, float* __restrict__ hend) {
  const int idx = blockIdx.x * 256 + threadIdx.x;  // (b*768+d)*64+s
  const int s  = idx & 63;
  const int bd = idx >> 6;
  const int d  = bd % DIN;
  const float A = -__expf(A_log[(d << 6) + s]) * L2E;
  float h = 0.f;
#pragma unroll
  for (int c = 0; c < NCH; ++c) {
    float* p = hend + (size_t)c * 393216 + idx;
    const float e = *p;
    *p = h;
    h = h * __builtin_amdgcn_exp2f(A * dtsum[c * 6144 + bd]) + e;
  }
}

// Pass 2: scan seeded with h_in, produce y (bf16).
__global__ __launch_bounds__(256)
void scan_p2_k(const u16* __restrict__ dt, const u16* __restrict__ xc,
               const u16* __restrict__ xdb, const float* __restrict__ A_log,
               const float* __restrict__ hin, u16* __restrict__ y) {
  const int wave = (blockIdx.x << 2) + (threadIdx.x >> 6);
  const int lane = threadIdx.x & 63;
  const int cc  = wave / 1536;
  const int rem = wave - cc * 1536;
  const int b  = rem / 192;
  const int d0 = (rem - b * 192) << 2;
  const int sg = lane & 15;
  const int d  = d0 + (lane >> 4);
  const int s4 = sg << 2;
  const float A0 = -__expf(A_log[(d << 6) + s4 + 0]) * L2E;
  const float A1 = -__expf(A_log[(d << 6) + s4 + 1]) * L2E;
  const float A2 = -__expf(A_log[(d << 6) + s4 + 2]) * L2E;
  const float A3 = -__expf(A_log[(d << 6) + s4 + 3]) * L2E;
  const size_t base = ((size_t)((cc << 3) + b) * DIN + d) * 64 + s4;
  const float4 hv = *(const float4*)(hin + base);
  float h0 = hv.x, h1 = hv.y, h2 = hv.z, h3 = hv.w;
  const size_t row0 = (size_t)b * LSEQ + (size_t)cc * LCH;
  const u16* pdt = dt + row0 * DIN + d;
  const u16* pxc = xc + row0 * DIN + d;
  const u16* pB  = xdb + row0 * 152 + 24 + s4;
  const u16* pC  = xdb + row0 * 152 + 88 + s4;
  u16* py = y + row0 * DIN + d;
#pragma unroll 4
  for (int t = 0; t < LCH; ++t) {
    const float dtv = bf2f(*pdt);
    const float xv  = bf2f(*pxc);
    const ushort4 Bv = *(const ushort4*)pB;
    const ushort4 Cv = *(const ushort4*)pC;
    pdt += DIN; pxc += DIN; pB += 152; pC += 152;
    const float dtx = dtv * xv;
    h0 = h0 * __builtin_amdgcn_exp2f(dtv * A0) + dtx * bf2f(Bv.x);
    h1 = h1 * __builtin_amdgcn_exp2f(dtv * A1) + dtx * bf2f(Bv.y);
    h2 = h2 * __builtin_amdgcn_exp2f(dtv * A2) + dtx * bf2f(Bv.z);
    h3 = h3 * __builtin_amdgcn_exp2f(dtv * A3) + dtx * bf2f(Bv.w);
    float p = h0 * bf2f(Cv.x) + h1 * bf2f(Cv.y) + h2 * bf2f(Cv.z) + h3 * bf2f(Cv.w);
    p += __shfl_xor(p, 1);
    p += __shfl_xor(p, 2);
    p += __shfl_xor(p, 4);
    p += __shfl_xor(p, 8);
    if (sg == 0) *py = f2b(p);
    py += DIN;
  }
}

// y <- (y + xc*Dp) * silu(z), in place (bf16)
__global__ __launch_bounds__(256)
void gate_k(u16* __restrict__ y, const u16* __restrict__ xc,
            const u16* __restrict__ zb, const float* __restrict__ Dp) {
  const size_t idx = (size_t)blockIdx.x * 256 + threadIdx.x;  // NT*768
  const int d = (int)(idx % DIN);
  const float zz = bf2f(zb[idx]);
  const float sig = zz / (1.f + __expf(-zz));
  const float v = (bf2f(y[idx]) + bf2f(xc[idx]) * Dp[d]) * sig;
  y[idx] = f2b(v);
}

// 3x3 depthwise conv (64x64 grid, pad 1) + exact GELU on a 768-channel half.
__global__ __launch_bounds__(256)
void dw_gelu_k(const u16* __restrict__ f1, const float* __restrict__ ww,
               const float* __restrict__ wb, u16* __restrict__ f2h, int co) {
  const size_t idx = (size_t)blockIdx.x * 256 + threadIdx.x;  // NT*768
  const int cl = (int)(idx % DIN);
  const int c = co + cl;
  const size_t row = idx / DIN;
  const int n = (int)(row & (LSEQ - 1));
  const size_t bb = row >> 12;
  const int i = n >> 6, jj = n & 63;
  float acc = wb[c];
#pragma unroll
  for (int di = -1; di <= 1; ++di) {
    const int ii = i + di;
    if (ii < 0 || ii > 63) continue;
#pragma unroll
    for (int dj = -1; dj <= 1; ++dj) {
      const int j2 = jj + dj;
      if (j2 < 0 || j2 > 63) continue;
      const size_t r2 = (bb << 12) + ((size_t)ii << 6) + j2;
      acc = fmaf(bf2f(f1[r2 * HIDC + c]), ww[c * 9 + (di + 1) * 3 + (dj + 1)], acc);
    }
  }
  const float gel = 0.5f * acc * (1.f + erff(acc * 0.70710678118654752f));
  f2h[idx] = f2b(gel);
}

// ---------------------------------------------------------------------------
extern "C" void kernel_launch(void* const* d_in, const int* in_sizes, int n_in,
                              void* d_out, int out_size, void* d_ws, size_t ws_size,
                              hipStream_t stream) {
  const float* x     = (const float*)d_in[0];
  const float* g1    = (const float*)d_in[3];
  const float* be1   = (const float*)d_in[4];
  const float* W_in  = (const float*)d_in[5];
  const float* convw = (const float*)d_in[6];
  const float* convb = (const float*)d_in[7];
  const float* W_xp  = (const float*)d_in[8];
  const float* W_dt  = (const float*)d_in[9];
  const float* b_dt  = (const float*)d_in[10];
  const float* A_log = (const float*)d_in[11];
  const float* Dp    = (const float*)d_in[12];
  const float* W_out = (const float*)d_in[13];
  const float* g2    = (const float*)d_in[14];
  const float* be2   = (const float*)d_in[15];
  const float* W1    = (const float*)d_in[16];
  const float* b1    = (const float*)d_in[17];
  const float* dww   = (const float*)d_in[18];
  const float* dwb   = (const float*)d_in[19];
  const float* W2    = (const float*)d_in[20];
  const float* b2    = (const float*)d_in[21];
  float* out = (float*)d_out;

  char* ws = (char*)d_ws;
  u16*   r0    = (u16*)(ws + OFF_R0);    // xr / dt / z
  u16*   xc_b  = (u16*)(ws + OFF_XC);
  u16*   xdb_b = (u16*)(ws + OFF_XDB);
  u16*   dtA_b = (u16*)(ws + OFF_DTA);
  u16*   xn_b  = (u16*)(ws + OFF_XN);
  u16*   y_b   = (u16*)(ws + OFF_Y);
  float* x2    = (float*)(ws + OFF_X2);
  float* hend  = (float*)(ws + OFF_HEND);
  float* dtsum = (float*)(ws + OFF_DTSUM);
  u16*   wb    = (u16*)(ws + OFF_WB);
  u16*   f1_b  = r0;                      // spans R0+XC (both dead then)
  u16*   f2h_b = xdb_b;                   // spans XDB.. (all dead then)

  // weights -> bf16 (W2 half-split, W_dt padded)
  convert_w_k<<<W_TOTAL / 256, 256, 0, stream>>>(W_in, W_xp, W_out, W1, W2, W_dt, wb);
  // LN1
  ln_k<<<NT / 4, 256, 0, stream>>>(x, g1, be1, xn_b);
  // xr = xn1 @ W_in[:768]^T
  gemm128_k<1, 0><<<dim3(6, 256), 256, 0, stream>>>(xn_b, wb + WOF_WIN, r0, nullptr, nullptr, DIN, DIMC);
  // causal dwconv1d + SiLU
  conv_silu_k<<<(NT * DIN) / 256, 256, 0, stream>>>(r0, convw, convb, xc_b);
  // xdb = xc @ W_xproj^T (bf16) — N=152 stays on the guarded 64^2 kernel
  gemm_k<1, 0><<<dim3(3, 512), 256, 0, stream>>>(xc_b, wb + WOF_WXP, xdb_b, nullptr, nullptr, 152, DIN);
  // dt = softplus(xdb[:, :24] @ W_dt^T + b_dt)  (overwrites xr in R0)
  pad_dt_k<<<(NT * 32) / 256, 256, 0, stream>>>(xdb_b, dtA_b);
  gemm128_k<1, 1><<<dim3(6, 256), 256, 0, stream>>>(dtA_b, wb + WOF_WDT, r0, b_dt, nullptr, DIN, 32);
  // chunked selective scan: pass1 -> combine -> pass2
  scan_p1_k<<<(NCH * 1536) / 4, 256, 0, stream>>>(r0, xc_b, xdb_b, A_log, hend, dtsum);
  scan_comb_k<<<393216 / 256, 256, 0, stream>>>(A_log, dtsum, hend);
  scan_p2_k<<<(NCH * 1536) / 4, 256, 0, stream>>>(r0, xc_b, xdb_b, A_log, hend, y_b);
  // z = xn1 @ W_in[768:]^T  (overwrites dt in R0)
  gemm128_k<1, 0><<<dim3(6, 256), 256, 0, stream>>>(xn_b, wb + WOF_WIN + 294912, r0, nullptr, nullptr, DIN, DIMC);
  // gate in place: y <- (y + xc*Dp) * silu(z)
  gate_k<<<(NT * DIN) / 256, 256, 0, stream>>>(y_b, xc_b, r0, Dp);
  // x2 = x + yg @ W_out^T  (f32)
  gemm128_k<0, 0><<<dim3(3, 256), 256, 0, stream>>>(y_b, wb + WOF_WOUT, x2, nullptr, x, DIMC, DIN);
  // LN2
  ln_k<<<NT / 4, 256, 0, stream>>>(x2, g2, be2, xn_b);
  // f1 = xn2 @ W1^T + b1  (spans R0+XC)
  gemm128_k<1, 0><<<dim3(12, 256), 256, 0, stream>>>(xn_b, wb + WOF_W1, f1_b, b1, nullptr, HIDC, DIMC);
  // half 0: 3x3 depthwise + GELU, then out = x2 + b2 + f2a @ W2a^T
  dw_gelu_k<<<(NT * DIN) / 256, 256, 0, stream>>>(f1_b, dww, dwb, f2h_b, 0);
  gemm128_k<0, 0><<<dim3(3, 256), 256, 0, stream>>>(f2h_b, wb + WOF_W2, out, b2, x2, DIMC, DIN);
  // half 1: out += f2b @ W2b^T
  dw_gelu_k<<<(NT * DIN) / 256, 256, 0, stream>>>(f1_b, dww, dwb, f2h_b, DIN);
  gemm128_k<0, 0><<<dim3(3, 256), 256, 0, stream>>>(f2h_b, wb + WOF_W2 + 294912, out, nullptr, out, DIMC, DIN);
}